// Round 7
// baseline (1287.211 us; speedup 1.0000x reference)
//
#include <hip/hip_runtime.h>

#define NV 20000
#define NNZE 6400000
#define KD 1280          // K = B * C_IN * R_IN
#define ND 512           // C_OUT * R_OUT
#define MROWS 20000
#define NR 1600000       // NV * 80 agg rows
#define RPB 256          // rows per bucket
#define NB 6250          // NR / RPB buckets
#define NBLK 4           // ceil(NB / 2048) scan blocks

typedef __attribute__((ext_vector_type(8))) short short8;
typedef __attribute__((ext_vector_type(4))) float f32x4;

// exact RNE f32 -> bf16 (finite inputs)
static __device__ __forceinline__ unsigned short f2bf(float f) {
    unsigned int u = __float_as_uint(f);
    return (unsigned short)((u + 0x7FFFu + ((u >> 16) & 1u)) >> 16);
}

__global__ __launch_bounds__(256) void zero_u32(unsigned int* __restrict__ p, int n) {
    int i = blockIdx.x * 256 + threadIdx.x;
    if (i < n) p[i] = 0u;
}

// lwT[n][k] (bf16, n-major) where lw[k][n] = weights[o*KD + src], n = o*16+j
__global__ __launch_bounds__(256) void build_lwT_kernel(
        const float* __restrict__ w, unsigned short* __restrict__ lwT) {
    int idx = blockIdx.x * 256 + threadIdx.x;           // < 512*1280
    int n = idx / KD;
    int k = idx - n * KD;
    int o = n >> 4, j = n & 15;
    int ci = k / 80;
    int i  = k - ci * 80;
    int t  = i / 5, p = i - t * 5;
    int src = ci * 80 + ((t + j) & 15) * 5 + p;
    lwT[idx] = f2bf(w[o * KD + src]);
}

// count edges per bucket (bucket = row >> 8); A[NB] counters (L2-hot, 25KB)
__global__ __launch_bounds__(256) void hist_kernel(
        const int* __restrict__ rows, unsigned int* __restrict__ A) {
    int e = blockIdx.x * 256 + threadIdx.x;             // grid exact = NNZE
    atomicAdd(&A[rows[e] >> 8], 1u);
}

// in-place block-local exclusive scan of A[NB]; bsum[b] = block total
__global__ __launch_bounds__(256) void scan1_kernel(
        unsigned int* __restrict__ A, unsigned int* __restrict__ bsum) {
    __shared__ unsigned int sh[256];
    int tid  = threadIdx.x;
    int base = blockIdx.x * 2048 + tid * 8;
    unsigned int v[8];
    unsigned int run = 0;
#pragma unroll
    for (int q = 0; q < 8; q++) {
        unsigned int t = (base + q < NB) ? A[base + q] : 0u;
        v[q] = run;                 // thread-local exclusive
        run += t;
    }
    sh[tid] = run;
    __syncthreads();
    unsigned int own = run;
    for (int ofs = 1; ofs < 256; ofs <<= 1) {           // Hillis-Steele inclusive
        unsigned int t = (tid >= ofs) ? sh[tid - ofs] : 0u;
        __syncthreads();
        sh[tid] += t;
        __syncthreads();
    }
    unsigned int excl = sh[tid] - own;
#pragma unroll
    for (int q = 0; q < 8; q++)
        if (base + q < NB) A[base + q] = excl + v[q];
    if (tid == 255) bsum[blockIdx.x] = sh[255];
}

// exclusive scan of bsum[NBLK] in place (single block)
__global__ __launch_bounds__(64) void scan2_kernel(unsigned int* __restrict__ bsum) {
    __shared__ unsigned int sh[64];
    int tid = threadIdx.x;
    unsigned int v = (tid < NBLK) ? bsum[tid] : 0u;
    sh[tid] = v;
    __syncthreads();
    for (int ofs = 1; ofs < 64; ofs <<= 1) {
        unsigned int t = (tid >= ofs) ? sh[tid - ofs] : 0u;
        __syncthreads();
        sh[tid] += t;
        __syncthreads();
    }
    if (tid < NBLK) bsum[tid] = sh[tid] - v;            // exclusive
}

// scatter edges into bucket-sorted order. 6250 sequential write streams ->
// L2 line-fill works (predict WRITE ~= payload 51MB, not 8x amplified).
// entry = (val_bits, col<<8 | row&255). After: A[b] = local inclusive prefix.
__global__ __launch_bounds__(256) void reorder_kernel(
        const int* __restrict__ rows, const float* __restrict__ vals,
        const int* __restrict__ cols, unsigned int* __restrict__ A,
        const unsigned int* __restrict__ bsum, uint2* __restrict__ entries) {
    int e = blockIdx.x * 256 + threadIdx.x;             // grid exact = NNZE
    int r = rows[e];
    int b = r >> 8;
    unsigned int pos = bsum[b >> 11] + atomicAdd(&A[b], 1u);
    entries[pos] = make_uint2(__float_as_uint(vals[e]),
                              ((unsigned int)cols[e] << 8) | (unsigned int)(r & 255));
}

// one block per bucket: accumulate 256 rows x 16 ch in LDS (f32 atomics),
// write out as bf16. 16-thread group per edge (ch = tid&15); entries[p] read
// is identical across the group -> coalescer merges; x row (64B) is L2-hot.
__global__ __launch_bounds__(256) void accum_kernel(
        const uint2* __restrict__ entries, const unsigned int* __restrict__ A,
        const unsigned int* __restrict__ bsum, const float* __restrict__ x,
        unsigned short* __restrict__ agg) {
    __shared__ float lacc[RPB * 16];                    // 16 KB
    int tid = threadIdx.x;
    int b   = blockIdx.x;
#pragma unroll
    for (int q = 0; q < 4; q++)
        *(f32x4*)&lacc[(q * 256 + tid) * 4] = (f32x4){0.f, 0.f, 0.f, 0.f};
    __syncthreads();

    unsigned int start = (b > 0) ? (A[b - 1] + bsum[(b - 1) >> 11]) : 0u;
    unsigned int end   = A[b] + bsum[b >> 11];
    int ch = tid & 15;
    for (unsigned int p = start + (tid >> 4); p < end; p += 16) {
        uint2 s = entries[p];
        float v = __uint_as_float(s.x);
        int col = (int)(s.y >> 8);
        int lr  = (int)(s.y & 255);
        atomicAdd(&lacc[lr * 16 + ch], v * x[(col << 4) + ch]);
    }
    __syncthreads();

    // writeout: 4096 f32 -> bf16, 2 rounds x 256 threads x 8 elems (16B stores)
#pragma unroll
    for (int rd = 0; rd < 2; rd++) {
        int eo = rd * 2048 + tid * 8;
        f32x4 lo = *(const f32x4*)&lacc[eo];
        f32x4 hi = *(const f32x4*)&lacc[eo + 4];
        short8 o;
        o[0] = (short)f2bf(lo.x); o[1] = (short)f2bf(lo.y);
        o[2] = (short)f2bf(lo.z); o[3] = (short)f2bf(lo.w);
        o[4] = (short)f2bf(hi.x); o[5] = (short)f2bf(hi.y);
        o[6] = (short)f2bf(hi.z); o[7] = (short)f2bf(hi.w);
        *(short8*)(agg + (size_t)b * (RPB * 16) + eo) = o;
    }
}

// C[M][512] = Abf[M][1280] * lwT^T ; bf16 MFMA 16x16x32, 128x128 tile, BK=64.
// Both operands staged via global_load_lds (linear LDS dest, inverse-pre-swizzled
// global source, swizzle cb ^= (row&7)<<4). A rows >= MROWS clamp to MROWS-1
// (epilogue masks those stores).
__global__ __launch_bounds__(256) void gemm_kernel(
        const unsigned short* __restrict__ Abf, const unsigned short* __restrict__ lwT,
        float* __restrict__ C) {
    __shared__ __align__(16) char lds[2 * 128 * 64 * 2];   // As 16KB | Bs 16KB
    char* As = lds;
    char* Bs = lds + 16384;

    int tid  = threadIdx.x;
    int lane = tid & 63;
    int wid  = tid >> 6;
    int wr = wid >> 1, wc = wid & 1;       // 2x2 waves, 64x64 each
    int m0 = blockIdx.x * 128;
    int n0 = blockIdx.y * 128;
    int l15 = lane & 15;
    int l4  = lane >> 4;

    f32x4 acc[4][4] = {};

    for (int k0 = 0; k0 < KD; k0 += 64) {
#pragma unroll
        for (int rd = 0; rd < 4; rd++) {
            int idx  = rd * 256 + tid;
            int trow = idx >> 3;                  // 0..127 (LDS row)
            int cb   = (idx & 7) * 16;            // byte in 128B row slice
            int swz  = cb ^ ((trow & 7) << 4);
            int gr   = m0 + trow;
            if (gr > MROWS - 1) gr = MROWS - 1;   // clamp; stores masked later
            size_t asrc = (size_t)gr * (KD * 2) + (size_t)(k0 * 2) + swz;
            __builtin_amdgcn_global_load_lds(
                (const __attribute__((address_space(1))) void*)((const char*)Abf + asrc),
                (__attribute__((address_space(3))) void*)(As + rd * 4096 + wid * 1024),
                16, 0, 0);
            size_t bsrc = (size_t)(n0 + trow) * (KD * 2) + (size_t)(k0 * 2) + swz;
            __builtin_amdgcn_global_load_lds(
                (const __attribute__((address_space(1))) void*)((const char*)lwT + bsrc),
                (__attribute__((address_space(3))) void*)(Bs + rd * 4096 + wid * 1024),
                16, 0, 0);
        }

        __syncthreads();   // compiler drains vmcnt before barrier (proven R4)

#pragma unroll
        for (int ks = 0; ks < 2; ks++) {
            short8 af[4], bf[4];
            int kb = ks * 64 + l4 * 16;
#pragma unroll
            for (int m = 0; m < 4; m++) {
                int r = wr * 64 + m * 16 + l15;
                af[m] = *(const short8*)(As + r * 128 + (kb ^ ((r & 7) << 4)));
            }
#pragma unroll
            for (int n = 0; n < 4; n++) {
                int r = wc * 64 + n * 16 + l15;
                bf[n] = *(const short8*)(Bs + r * 128 + (kb ^ ((r & 7) << 4)));
            }
#pragma unroll
            for (int m = 0; m < 4; m++)
#pragma unroll
                for (int n = 0; n < 4; n++)
                    acc[m][n] = __builtin_amdgcn_mfma_f32_16x16x32_bf16(
                                    af[m], bf[n], acc[m][n], 0, 0, 0);
        }

        __syncthreads();
    }

    // epilogue: D col = lane&15, row = (lane>>4)*4 + reg
#pragma unroll
    for (int m = 0; m < 4; m++) {
        int row_b = m0 + wr * 64 + m * 16 + l4 * 4;
#pragma unroll
        for (int n = 0; n < 4; n++) {
            int col = n0 + wc * 64 + n * 16 + l15;
#pragma unroll
            for (int r = 0; r < 4; r++) {
                int row = row_b + r;
                if (row < MROWS) C[(size_t)row * ND + col] = acc[m][n][r];
            }
        }
    }
}

extern "C" void kernel_launch(void* const* d_in, const int* in_sizes, int n_in,
                              void* d_out, int out_size, void* d_ws, size_t ws_size,
                              hipStream_t stream) {
    const float* x         = (const float*)d_in[0];
    const float* weights   = (const float*)d_in[1];
    const float* conn_vals = (const float*)d_in[2];
    const int*   conn_rows = (const int*)d_in[3];
    const int*   conn_cols = (const int*)d_in[4];
    float* out = (float*)d_out;

    // ws layout (103.74 MB total, all 16B-aligned):
    char* ws = (char*)d_ws;
    unsigned short* agg     = (unsigned short*)ws;               // 51,200,000 B (NR*16 bf16)
    uint2*          entries = (uint2*)(ws + 51200000);           // 51,200,000 B (NNZE*8)
    unsigned int*   A       = (unsigned int*)(ws + 102400000);   //     25,000 B (NB*4)
    unsigned int*   bsum    = (unsigned int*)(ws + 102425600);   //      2,048 B
    unsigned short* lwT     = (unsigned short*)(ws + 102427648); //  1,310,720 B

    hipLaunchKernelGGL(build_lwT_kernel, dim3((ND * KD) / 256), dim3(256), 0, stream,
                       weights, lwT);
    hipLaunchKernelGGL(zero_u32, dim3((NB + 255) / 256), dim3(256), 0, stream, A, NB);
    hipLaunchKernelGGL(hist_kernel, dim3(NNZE / 256), dim3(256), 0, stream,
                       conn_rows, A);
    hipLaunchKernelGGL(scan1_kernel, dim3(NBLK), dim3(256), 0, stream, A, bsum);
    hipLaunchKernelGGL(scan2_kernel, dim3(1), dim3(64), 0, stream, bsum);
    hipLaunchKernelGGL(reorder_kernel, dim3(NNZE / 256), dim3(256), 0, stream,
                       conn_rows, conn_vals, conn_cols, A, bsum, entries);
    hipLaunchKernelGGL(accum_kernel, dim3(NB), dim3(256), 0, stream,
                       entries, A, bsum, x, agg);
    hipLaunchKernelGGL(gemm_kernel, dim3((MROWS + 127) / 128, ND / 128), dim3(256),
                       0, stream, agg, lwT, out);
}

// Round 10
// 1252.721 us; speedup vs baseline: 1.0275x; 1.0275x over previous
//
#include <hip/hip_runtime.h>

#define NV 20000
#define NNZE 6400000
#define KD 1280          // K = B * C_IN * R_IN
#define ND 512           // C_OUT * R_OUT
#define MROWS 20000
#define NR 1600000       // NV * 80 agg rows
#define RPB 256          // rows per bucket
#define NB 6250          // NR / RPB buckets
#define NREP 16          // replica streams per bucket (kills fetch-add chains)
#define NCTR (NB * NREP) // 100000 logical counters
#define NBLK 49          // ceil(NCTR / 2048) scan blocks

typedef __attribute__((ext_vector_type(8))) short short8;
typedef __attribute__((ext_vector_type(4))) float f32x4;

// exact RNE f32 -> bf16 (finite inputs)
static __device__ __forceinline__ unsigned short f2bf(float f) {
    unsigned int u = __float_as_uint(f);
    return (unsigned short)((u + 0x7FFFu + ((u >> 16) & 1u)) >> 16);
}

__global__ __launch_bounds__(256) void zero_u32(unsigned int* __restrict__ p, int n) {
    int i = blockIdx.x * 256 + threadIdx.x;
    if (i < n) p[i] = 0u;
}

// lwT[n][k] (bf16, n-major) where lw[k][n] = weights[o*KD + src], n = o*16+j
__global__ __launch_bounds__(256) void build_lwT_kernel(
        const float* __restrict__ w, unsigned short* __restrict__ lwT) {
    int idx = blockIdx.x * 256 + threadIdx.x;           // < 512*1280
    int n = idx / KD;
    int k = idx - n * KD;
    int o = n >> 4, j = n & 15;
    int ci = k / 80;
    int i  = k - ci * 80;
    int t  = i / 5, p = i - t * 5;
    int src = ci * 80 + ((t + j) & 15) * 5 + p;
    lwT[idx] = f2bf(w[o * KD + src]);
}

// count edges per (bucket, replica); non-returning atomics pipeline at L2
__global__ __launch_bounds__(256) void hist_kernel(
        const int* __restrict__ rows, unsigned int* __restrict__ A) {
    int e = blockIdx.x * 256 + threadIdx.x;             // grid exact = NNZE
    atomicAdd(&A[(rows[e] >> 8) * NREP + (e & (NREP - 1))], 1u);
}

// in-place block-local exclusive scan of A[NCTR]; bsum[b] = block total
__global__ __launch_bounds__(256) void scan1_kernel(
        unsigned int* __restrict__ A, unsigned int* __restrict__ bsum) {
    __shared__ unsigned int sh[256];
    int tid  = threadIdx.x;
    int base = blockIdx.x * 2048 + tid * 8;
    unsigned int v[8];
    unsigned int run = 0;
#pragma unroll
    for (int q = 0; q < 8; q++) {
        unsigned int t = (base + q < NCTR) ? A[base + q] : 0u;
        v[q] = run;                 // thread-local exclusive
        run += t;
    }
    sh[tid] = run;
    __syncthreads();
    unsigned int own = run;
    for (int ofs = 1; ofs < 256; ofs <<= 1) {           // Hillis-Steele inclusive
        unsigned int t = (tid >= ofs) ? sh[tid - ofs] : 0u;
        __syncthreads();
        sh[tid] += t;
        __syncthreads();
    }
    unsigned int excl = sh[tid] - own;
#pragma unroll
    for (int q = 0; q < 8; q++)
        if (base + q < NCTR) A[base + q] = excl + v[q];
    if (tid == 255) bsum[blockIdx.x] = sh[255];
}

// exclusive scan of bsum[NBLK] in place (single block)
__global__ __launch_bounds__(64) void scan2_kernel(unsigned int* __restrict__ bsum) {
    __shared__ unsigned int sh[64];
    int tid = threadIdx.x;
    unsigned int v = (tid < NBLK) ? bsum[tid] : 0u;
    sh[tid] = v;
    __syncthreads();
    for (int ofs = 1; ofs < 64; ofs <<= 1) {
        unsigned int t = (tid >= ofs) ? sh[tid - ofs] : 0u;
        __syncthreads();
        sh[tid] += t;
        __syncthreads();
    }
    if (tid < NBLK) bsum[tid] = sh[tid] - v;            // exclusive
}

// scatter edges into (bucket,replica)-sorted order. Chain depth per counter =
// ~64 (vs 1024 unreplicated); sub-streams concatenate so bucket stays contiguous.
// entry = (val_bits, col<<8 | row&255). After: A[i] = local inclusive prefix.
__global__ __launch_bounds__(256) void reorder_kernel(
        const int* __restrict__ rows, const float* __restrict__ vals,
        const int* __restrict__ cols, unsigned int* __restrict__ A,
        const unsigned int* __restrict__ bsum, uint2* __restrict__ entries) {
    int e = blockIdx.x * 256 + threadIdx.x;             // grid exact = NNZE
    int r = rows[e];
    int i = (r >> 8) * NREP + (e & (NREP - 1));
    unsigned int pos = bsum[i >> 11] + atomicAdd(&A[i], 1u);
    entries[pos] = make_uint2(__float_as_uint(vals[e]),
                              ((unsigned int)cols[e] << 8) | (unsigned int)(r & 255));
}

// one block per bucket: accumulate 256 rows x 16 ch in LDS (f32 atomics), write
// bf16. 16 threads per edge (ch = tid&15). 4x batched unroll for memory-level
// parallelism (R7: unbatched chain was 800cy/iter, VALUBusy 4.6%).
__global__ __launch_bounds__(256) void accum_kernel(
        const uint2* __restrict__ entries, const unsigned int* __restrict__ A,
        const unsigned int* __restrict__ bsum, const float* __restrict__ x,
        unsigned short* __restrict__ agg) {
    __shared__ float lacc[RPB * 16];                    // 16 KB
    int tid = threadIdx.x;
    int b   = blockIdx.x;
#pragma unroll
    for (int q = 0; q < 4; q++)
        *(f32x4*)&lacc[(q * 256 + tid) * 4] = (f32x4){0.f, 0.f, 0.f, 0.f};
    __syncthreads();

    int i0 = b * NREP;
    int i1 = i0 + NREP - 1;
    unsigned int start = (i0 > 0) ? (A[i0 - 1] + bsum[(i0 - 1) >> 11]) : 0u;
    unsigned int end   = A[i1] + bsum[i1 >> 11];
    int ch = tid & 15;

    unsigned int p = start + (tid >> 4);
    // batched x4: all 4 loads issued before any use -> 4-way MLP
    for (; p + 48 < end; p += 64) {
        uint2 e0 = entries[p];
        uint2 e1 = entries[p + 16];
        uint2 e2 = entries[p + 32];
        uint2 e3 = entries[p + 48];
        float x0 = x[((e0.y >> 8) << 4) + ch];
        float x1 = x[((e1.y >> 8) << 4) + ch];
        float x2 = x[((e2.y >> 8) << 4) + ch];
        float x3 = x[((e3.y >> 8) << 4) + ch];
        atomicAdd(&lacc[(e0.y & 255) * 16 + ch], __uint_as_float(e0.x) * x0);
        atomicAdd(&lacc[(e1.y & 255) * 16 + ch], __uint_as_float(e1.x) * x1);
        atomicAdd(&lacc[(e2.y & 255) * 16 + ch], __uint_as_float(e2.x) * x2);
        atomicAdd(&lacc[(e3.y & 255) * 16 + ch], __uint_as_float(e3.x) * x3);
    }
    for (; p < end; p += 16) {
        uint2 s = entries[p];
        atomicAdd(&lacc[(s.y & 255) * 16 + ch],
                  __uint_as_float(s.x) * x[((s.y >> 8) << 4) + ch]);
    }
    __syncthreads();

    // writeout: 4096 f32 -> bf16, 2 rounds x 256 threads x 8 elems (16B stores)
#pragma unroll
    for (int rd = 0; rd < 2; rd++) {
        int eo = rd * 2048 + tid * 8;
        f32x4 lo = *(const f32x4*)&lacc[eo];
        f32x4 hi = *(const f32x4*)&lacc[eo + 4];
        short8 o;
        o[0] = (short)f2bf(lo.x); o[1] = (short)f2bf(lo.y);
        o[2] = (short)f2bf(lo.z); o[3] = (short)f2bf(lo.w);
        o[4] = (short)f2bf(hi.x); o[5] = (short)f2bf(hi.y);
        o[6] = (short)f2bf(hi.z); o[7] = (short)f2bf(hi.w);
        *(short8*)(agg + (size_t)b * (RPB * 16) + eo) = o;
    }
}

// C[M][512] = Abf[M][1280] * lwT^T ; bf16 MFMA 16x16x32, 128x128 tile, BK=64.
// Both operands staged via global_load_lds (linear LDS dest, inverse-pre-swizzled
// global source, swizzle cb ^= (row&7)<<4). A rows >= MROWS clamp to MROWS-1
// (epilogue masks those stores).
__global__ __launch_bounds__(256) void gemm_kernel(
        const unsigned short* __restrict__ Abf, const unsigned short* __restrict__ lwT,
        float* __restrict__ C) {
    __shared__ __align__(16) char lds[2 * 128 * 64 * 2];   // As 16KB | Bs 16KB
    char* As = lds;
    char* Bs = lds + 16384;

    int tid  = threadIdx.x;
    int lane = tid & 63;
    int wid  = tid >> 6;
    int wr = wid >> 1, wc = wid & 1;       // 2x2 waves, 64x64 each
    int m0 = blockIdx.x * 128;
    int n0 = blockIdx.y * 128;
    int l15 = lane & 15;
    int l4  = lane >> 4;

    f32x4 acc[4][4] = {};

    for (int k0 = 0; k0 < KD; k0 += 64) {
#pragma unroll
        for (int rd = 0; rd < 4; rd++) {
            int idx  = rd * 256 + tid;
            int trow = idx >> 3;                  // 0..127 (LDS row)
            int cb   = (idx & 7) * 16;            // byte in 128B row slice
            int swz  = cb ^ ((trow & 7) << 4);
            int gr   = m0 + trow;
            if (gr > MROWS - 1) gr = MROWS - 1;   // clamp; stores masked later
            size_t asrc = (size_t)gr * (KD * 2) + (size_t)(k0 * 2) + swz;
            __builtin_amdgcn_global_load_lds(
                (const __attribute__((address_space(1))) void*)((const char*)Abf + asrc),
                (__attribute__((address_space(3))) void*)(As + rd * 4096 + wid * 1024),
                16, 0, 0);
            size_t bsrc = (size_t)(n0 + trow) * (KD * 2) + (size_t)(k0 * 2) + swz;
            __builtin_amdgcn_global_load_lds(
                (const __attribute__((address_space(1))) void*)((const char*)lwT + bsrc),
                (__attribute__((address_space(3))) void*)(Bs + rd * 4096 + wid * 1024),
                16, 0, 0);
        }

        __syncthreads();   // compiler drains vmcnt before barrier (proven R4)

#pragma unroll
        for (int ks = 0; ks < 2; ks++) {
            short8 af[4], bf[4];
            int kb = ks * 64 + l4 * 16;
#pragma unroll
            for (int m = 0; m < 4; m++) {
                int r = wr * 64 + m * 16 + l15;
                af[m] = *(const short8*)(As + r * 128 + (kb ^ ((r & 7) << 4)));
            }
#pragma unroll
            for (int n = 0; n < 4; n++) {
                int r = wc * 64 + n * 16 + l15;
                bf[n] = *(const short8*)(Bs + r * 128 + (kb ^ ((r & 7) << 4)));
            }
#pragma unroll
            for (int m = 0; m < 4; m++)
#pragma unroll
                for (int n = 0; n < 4; n++)
                    acc[m][n] = __builtin_amdgcn_mfma_f32_16x16x32_bf16(
                                    af[m], bf[n], acc[m][n], 0, 0, 0);
        }

        __syncthreads();
    }

    // epilogue: D col = lane&15, row = (lane>>4)*4 + reg
#pragma unroll
    for (int m = 0; m < 4; m++) {
        int row_b = m0 + wr * 64 + m * 16 + l4 * 4;
#pragma unroll
        for (int n = 0; n < 4; n++) {
            int col = n0 + wc * 64 + n * 16 + l15;
#pragma unroll
            for (int r = 0; r < 4; r++) {
                int row = row_b + r;
                if (row < MROWS) C[(size_t)row * ND + col] = acc[m][n][r];
            }
        }
    }
}

extern "C" void kernel_launch(void* const* d_in, const int* in_sizes, int n_in,
                              void* d_out, int out_size, void* d_ws, size_t ws_size,
                              hipStream_t stream) {
    const float* x         = (const float*)d_in[0];
    const float* weights   = (const float*)d_in[1];
    const float* conn_vals = (const float*)d_in[2];
    const int*   conn_rows = (const int*)d_in[3];
    const int*   conn_cols = (const int*)d_in[4];
    float* out = (float*)d_out;

    // ws layout (104.11 MB total < 104.20 MB proven in R4; all 16B-aligned):
    char* ws = (char*)d_ws;
    unsigned short* agg     = (unsigned short*)ws;               // 51,200,000 B
    uint2*          entries = (uint2*)(ws + 51200000);           // 51,200,000 B
    unsigned int*   A       = (unsigned int*)(ws + 102400000);   //    400,000 B (NCTR*4)
    unsigned int*   bsum    = (unsigned int*)(ws + 102800000);   //        256 B
    unsigned short* lwT     = (unsigned short*)(ws + 102800256); //  1,310,720 B

    hipLaunchKernelGGL(build_lwT_kernel, dim3((ND * KD) / 256), dim3(256), 0, stream,
                       weights, lwT);
    hipLaunchKernelGGL(zero_u32, dim3((NCTR + 255) / 256), dim3(256), 0, stream, A, NCTR);
    hipLaunchKernelGGL(hist_kernel, dim3(NNZE / 256), dim3(256), 0, stream,
                       conn_rows, A);
    hipLaunchKernelGGL(scan1_kernel, dim3(NBLK), dim3(256), 0, stream, A, bsum);
    hipLaunchKernelGGL(scan2_kernel, dim3(1), dim3(64), 0, stream, bsum);
    hipLaunchKernelGGL(reorder_kernel, dim3(NNZE / 256), dim3(256), 0, stream,
                       conn_rows, conn_vals, conn_cols, A, bsum, entries);
    hipLaunchKernelGGL(accum_kernel, dim3(NB), dim3(256), 0, stream,
                       entries, A, bsum, x, agg);
    hipLaunchKernelGGL(gemm_kernel, dim3((MROWS + 127) / 128, ND / 128), dim3(256),
                       0, stream, agg, lwT, out);
}

// Round 12
// 1247.295 us; speedup vs baseline: 1.0320x; 1.0043x over previous
//
#include <hip/hip_runtime.h>

#define NV 20000
#define NNZE 6400000
#define KD 1280          // K = B * C_IN * R_IN
#define ND 512           // C_OUT * R_OUT
#define MROWS 20000
#define NR 1600000       // NV * 80 agg rows
#define RPB 256          // rows per bucket
#define NB 6250          // NR / RPB buckets
#define NREP 16          // replica streams per bucket (kills fetch-add chains)
#define NCTR (NB * NREP) // 100000 logical counters
#define NBLK 49          // ceil(NCTR / 2048) scan blocks

typedef __attribute__((ext_vector_type(8))) short short8;
typedef __attribute__((ext_vector_type(4))) float f32x4;

// exact RNE f32 -> bf16 (finite inputs)
static __device__ __forceinline__ unsigned short f2bf(float f) {
    unsigned int u = __float_as_uint(f);
    return (unsigned short)((u + 0x7FFFu + ((u >> 16) & 1u)) >> 16);
}

__global__ __launch_bounds__(256) void zero_u32(unsigned int* __restrict__ p, int n) {
    int i = blockIdx.x * 256 + threadIdx.x;
    if (i < n) p[i] = 0u;
}

// lwT[n][k] (bf16, n-major) where lw[k][n] = weights[o*KD + src], n = o*16+j
__global__ __launch_bounds__(256) void build_lwT_kernel(
        const float* __restrict__ w, unsigned short* __restrict__ lwT) {
    int idx = blockIdx.x * 256 + threadIdx.x;           // < 512*1280
    int n = idx / KD;
    int k = idx - n * KD;
    int o = n >> 4, j = n & 15;
    int ci = k / 80;
    int i  = k - ci * 80;
    int t  = i / 5, p = i - t * 5;
    int src = ci * 80 + ((t + j) & 15) * 5 + p;
    lwT[idx] = f2bf(w[o * KD + src]);
}

// count edges per (bucket, replica); non-returning atomics pipeline at L2
__global__ __launch_bounds__(256) void hist_kernel(
        const int* __restrict__ rows, unsigned int* __restrict__ A) {
    int e = blockIdx.x * 256 + threadIdx.x;             // grid exact = NNZE
    atomicAdd(&A[(rows[e] >> 8) * NREP + (e & (NREP - 1))], 1u);
}

// in-place block-local exclusive scan of A[NCTR]; bsum[b] = block total
__global__ __launch_bounds__(256) void scan1_kernel(
        unsigned int* __restrict__ A, unsigned int* __restrict__ bsum) {
    __shared__ unsigned int sh[256];
    int tid  = threadIdx.x;
    int base = blockIdx.x * 2048 + tid * 8;
    unsigned int v[8];
    unsigned int run = 0;
#pragma unroll
    for (int q = 0; q < 8; q++) {
        unsigned int t = (base + q < NCTR) ? A[base + q] : 0u;
        v[q] = run;                 // thread-local exclusive
        run += t;
    }
    sh[tid] = run;
    __syncthreads();
    unsigned int own = run;
    for (int ofs = 1; ofs < 256; ofs <<= 1) {           // Hillis-Steele inclusive
        unsigned int t = (tid >= ofs) ? sh[tid - ofs] : 0u;
        __syncthreads();
        sh[tid] += t;
        __syncthreads();
    }
    unsigned int excl = sh[tid] - own;
#pragma unroll
    for (int q = 0; q < 8; q++)
        if (base + q < NCTR) A[base + q] = excl + v[q];
    if (tid == 255) bsum[blockIdx.x] = sh[255];
}

// exclusive scan of bsum[NBLK] in place (single block)
__global__ __launch_bounds__(64) void scan2_kernel(unsigned int* __restrict__ bsum) {
    __shared__ unsigned int sh[64];
    int tid = threadIdx.x;
    unsigned int v = (tid < NBLK) ? bsum[tid] : 0u;
    sh[tid] = v;
    __syncthreads();
    for (int ofs = 1; ofs < 64; ofs <<= 1) {
        unsigned int t = (tid >= ofs) ? sh[tid - ofs] : 0u;
        __syncthreads();
        sh[tid] += t;
        __syncthreads();
    }
    if (tid < NBLK) bsum[tid] = sh[tid] - v;            // exclusive
}

// scatter edges into (bucket,replica)-sorted order. Chain depth per counter =
// ~64; sub-streams concatenate so bucket stays contiguous.
// entry = (val_bits, col<<8 | row&255). After: A[i] = local inclusive prefix.
__global__ __launch_bounds__(256) void reorder_kernel(
        const int* __restrict__ rows, const float* __restrict__ vals,
        const int* __restrict__ cols, unsigned int* __restrict__ A,
        const unsigned int* __restrict__ bsum, uint2* __restrict__ entries) {
    int e = blockIdx.x * 256 + threadIdx.x;             // grid exact = NNZE
    int r = rows[e];
    int i = (r >> 8) * NREP + (e & (NREP - 1));
    unsigned int pos = bsum[i >> 11] + atomicAdd(&A[i], 1u);
    entries[pos] = make_uint2(__float_as_uint(vals[e]),
                              ((unsigned int)cols[e] << 8) | (unsigned int)(r & 255));
}

// one block per bucket: accumulate 256 rows x 16 ch in LDS (f32 atomics), write
// bf16. 16 threads per edge (ch = tid&15).
// R10 lesson: source-level batching was re-serialized by the compiler
// (VGPR=12, VALUBusy 4.9%). Force 4-way MLP with inline-asm loads +
// explicit vmcnt(0) + sched_barrier(0) fences (rule #18: asm outputs are
// not tracked by compiler waitcnt logic, and reg-only uses can hoist past
// an asm waitcnt unless fenced).
__global__ __launch_bounds__(256) void accum_kernel(
        const uint2* __restrict__ entries, const unsigned int* __restrict__ A,
        const unsigned int* __restrict__ bsum, const float* __restrict__ x,
        unsigned short* __restrict__ agg) {
    __shared__ float lacc[RPB * 16];                    // 16 KB
    int tid = threadIdx.x;
    int b   = blockIdx.x;
#pragma unroll
    for (int q = 0; q < 4; q++)
        *(f32x4*)&lacc[(q * 256 + tid) * 4] = (f32x4){0.f, 0.f, 0.f, 0.f};
    __syncthreads();

    int i0 = b * NREP;
    int i1 = i0 + NREP - 1;
    unsigned int start = (i0 > 0) ? (A[i0 - 1] + bsum[(i0 - 1) >> 11]) : 0u;
    unsigned int end   = A[i1] + bsum[i1 >> 11];
    int ch = tid & 15;
    const float* xb = x + ch;

    unsigned int p = start + (tid >> 4);
    for (; p + 48 < end; p += 64) {
        const uint2* a0 = entries + p;
        const uint2* a1 = entries + p + 16;
        const uint2* a2 = entries + p + 32;
        const uint2* a3 = entries + p + 48;
        uint2 e0, e1, e2, e3;
        // 4 loads guaranteed in flight (compiler cannot split asm)
        asm volatile("global_load_dwordx2 %0, %1, off" : "=&v"(e0) : "v"(a0));
        asm volatile("global_load_dwordx2 %0, %1, off" : "=&v"(e1) : "v"(a1));
        asm volatile("global_load_dwordx2 %0, %1, off" : "=&v"(e2) : "v"(a2));
        asm volatile("global_load_dwordx2 %0, %1, off" : "=&v"(e3) : "v"(a3));
        asm volatile("s_waitcnt vmcnt(0)" ::: "memory");
        __builtin_amdgcn_sched_barrier(0);
        const float* q0 = xb + ((e0.y >> 8) << 4);
        const float* q1 = xb + ((e1.y >> 8) << 4);
        const float* q2 = xb + ((e2.y >> 8) << 4);
        const float* q3 = xb + ((e3.y >> 8) << 4);
        float x0, x1, x2, x3;
        asm volatile("global_load_dword %0, %1, off" : "=&v"(x0) : "v"(q0));
        asm volatile("global_load_dword %0, %1, off" : "=&v"(x1) : "v"(q1));
        asm volatile("global_load_dword %0, %1, off" : "=&v"(x2) : "v"(q2));
        asm volatile("global_load_dword %0, %1, off" : "=&v"(x3) : "v"(q3));
        asm volatile("s_waitcnt vmcnt(0)" ::: "memory");
        __builtin_amdgcn_sched_barrier(0);
        atomicAdd(&lacc[(e0.y & 255) * 16 + ch], __uint_as_float(e0.x) * x0);
        atomicAdd(&lacc[(e1.y & 255) * 16 + ch], __uint_as_float(e1.x) * x1);
        atomicAdd(&lacc[(e2.y & 255) * 16 + ch], __uint_as_float(e2.x) * x2);
        atomicAdd(&lacc[(e3.y & 255) * 16 + ch], __uint_as_float(e3.x) * x3);
    }
    for (; p < end; p += 16) {
        uint2 s = entries[p];
        atomicAdd(&lacc[(s.y & 255) * 16 + ch],
                  __uint_as_float(s.x) * x[((s.y >> 8) << 4) + ch]);
    }
    __syncthreads();

    // writeout: 4096 f32 -> bf16, 2 rounds x 256 threads x 8 elems (16B stores)
#pragma unroll
    for (int rd = 0; rd < 2; rd++) {
        int eo = rd * 2048 + tid * 8;
        f32x4 lo = *(const f32x4*)&lacc[eo];
        f32x4 hi = *(const f32x4*)&lacc[eo + 4];
        short8 o;
        o[0] = (short)f2bf(lo.x); o[1] = (short)f2bf(lo.y);
        o[2] = (short)f2bf(lo.z); o[3] = (short)f2bf(lo.w);
        o[4] = (short)f2bf(hi.x); o[5] = (short)f2bf(hi.y);
        o[6] = (short)f2bf(hi.z); o[7] = (short)f2bf(hi.w);
        *(short8*)(agg + (size_t)b * (RPB * 16) + eo) = o;
    }
}

// C[M][512] = Abf[M][1280] * lwT^T ; bf16 MFMA 16x16x32, 128x128 tile, BK=64.
// Both operands staged via global_load_lds (linear LDS dest, inverse-pre-swizzled
// global source, swizzle cb ^= (row&7)<<4). A rows >= MROWS clamp to MROWS-1
// (epilogue masks those stores).
__global__ __launch_bounds__(256) void gemm_kernel(
        const unsigned short* __restrict__ Abf, const unsigned short* __restrict__ lwT,
        float* __restrict__ C) {
    __shared__ __align__(16) char lds[2 * 128 * 64 * 2];   // As 16KB | Bs 16KB
    char* As = lds;
    char* Bs = lds + 16384;

    int tid  = threadIdx.x;
    int lane = tid & 63;
    int wid  = tid >> 6;
    int wr = wid >> 1, wc = wid & 1;       // 2x2 waves, 64x64 each
    int m0 = blockIdx.x * 128;
    int n0 = blockIdx.y * 128;
    int l15 = lane & 15;
    int l4  = lane >> 4;

    f32x4 acc[4][4] = {};

    for (int k0 = 0; k0 < KD; k0 += 64) {
#pragma unroll
        for (int rd = 0; rd < 4; rd++) {
            int idx  = rd * 256 + tid;
            int trow = idx >> 3;                  // 0..127 (LDS row)
            int cb   = (idx & 7) * 16;            // byte in 128B row slice
            int swz  = cb ^ ((trow & 7) << 4);
            int gr   = m0 + trow;
            if (gr > MROWS - 1) gr = MROWS - 1;   // clamp; stores masked later
            size_t asrc = (size_t)gr * (KD * 2) + (size_t)(k0 * 2) + swz;
            __builtin_amdgcn_global_load_lds(
                (const __attribute__((address_space(1))) void*)((const char*)Abf + asrc),
                (__attribute__((address_space(3))) void*)(As + rd * 4096 + wid * 1024),
                16, 0, 0);
            size_t bsrc = (size_t)(n0 + trow) * (KD * 2) + (size_t)(k0 * 2) + swz;
            __builtin_amdgcn_global_load_lds(
                (const __attribute__((address_space(1))) void*)((const char*)lwT + bsrc),
                (__attribute__((address_space(3))) void*)(Bs + rd * 4096 + wid * 1024),
                16, 0, 0);
        }

        __syncthreads();   // compiler drains vmcnt before barrier (proven R4)

#pragma unroll
        for (int ks = 0; ks < 2; ks++) {
            short8 af[4], bf[4];
            int kb = ks * 64 + l4 * 16;
#pragma unroll
            for (int m = 0; m < 4; m++) {
                int r = wr * 64 + m * 16 + l15;
                af[m] = *(const short8*)(As + r * 128 + (kb ^ ((r & 7) << 4)));
            }
#pragma unroll
            for (int n = 0; n < 4; n++) {
                int r = wc * 64 + n * 16 + l15;
                bf[n] = *(const short8*)(Bs + r * 128 + (kb ^ ((r & 7) << 4)));
            }
#pragma unroll
            for (int m = 0; m < 4; m++)
#pragma unroll
                for (int n = 0; n < 4; n++)
                    acc[m][n] = __builtin_amdgcn_mfma_f32_16x16x32_bf16(
                                    af[m], bf[n], acc[m][n], 0, 0, 0);
        }

        __syncthreads();
    }

    // epilogue: D col = lane&15, row = (lane>>4)*4 + reg
#pragma unroll
    for (int m = 0; m < 4; m++) {
        int row_b = m0 + wr * 64 + m * 16 + l4 * 4;
#pragma unroll
        for (int n = 0; n < 4; n++) {
            int col = n0 + wc * 64 + n * 16 + l15;
#pragma unroll
            for (int r = 0; r < 4; r++) {
                int row = row_b + r;
                if (row < MROWS) C[(size_t)row * ND + col] = acc[m][n][r];
            }
        }
    }
}

extern "C" void kernel_launch(void* const* d_in, const int* in_sizes, int n_in,
                              void* d_out, int out_size, void* d_ws, size_t ws_size,
                              hipStream_t stream) {
    const float* x         = (const float*)d_in[0];
    const float* weights   = (const float*)d_in[1];
    const float* conn_vals = (const float*)d_in[2];
    const int*   conn_rows = (const int*)d_in[3];
    const int*   conn_cols = (const int*)d_in[4];
    float* out = (float*)d_out;

    // ws layout (104.11 MB total < 104.20 MB proven in R4; all 16B-aligned):
    char* ws = (char*)d_ws;
    unsigned short* agg     = (unsigned short*)ws;               // 51,200,000 B
    uint2*          entries = (uint2*)(ws + 51200000);           // 51,200,000 B
    unsigned int*   A       = (unsigned int*)(ws + 102400000);   //    400,000 B (NCTR*4)
    unsigned int*   bsum    = (unsigned int*)(ws + 102800000);   //        256 B
    unsigned short* lwT     = (unsigned short*)(ws + 102800256); //  1,310,720 B

    hipLaunchKernelGGL(build_lwT_kernel, dim3((ND * KD) / 256), dim3(256), 0, stream,
                       weights, lwT);
    hipLaunchKernelGGL(zero_u32, dim3((NCTR + 255) / 256), dim3(256), 0, stream, A, NCTR);
    hipLaunchKernelGGL(hist_kernel, dim3(NNZE / 256), dim3(256), 0, stream,
                       conn_rows, A);
    hipLaunchKernelGGL(scan1_kernel, dim3(NBLK), dim3(256), 0, stream, A, bsum);
    hipLaunchKernelGGL(scan2_kernel, dim3(1), dim3(64), 0, stream, bsum);
    hipLaunchKernelGGL(reorder_kernel, dim3(NNZE / 256), dim3(256), 0, stream,
                       conn_rows, conn_vals, conn_cols, A, bsum, entries);
    hipLaunchKernelGGL(accum_kernel, dim3(NB), dim3(256), 0, stream,
                       entries, A, bsum, x, agg);
    hipLaunchKernelGGL(gemm_kernel, dim3((MROWS + 127) / 128, ND / 128), dim3(256),
                       0, stream, agg, lwT, out);
}